// Round 3
// baseline (140.868 us; speedup 1.0000x reference)
//
#include <hip/hip_runtime.h>

#define B 8
#define N 2048
#define KF 256
#define DF 64
#define LOG2E 1.44269504088896340736f

typedef __attribute__((ext_vector_type(8))) short short8;   // 8 bf16 (4 VGPRs)
typedef __attribute__((ext_vector_type(4))) float float4v;  // MFMA C/D frag

__device__ __forceinline__ float fexp2(float x) {
#if __has_builtin(__builtin_amdgcn_exp2f)
    return __builtin_amdgcn_exp2f(x);
#else
    return exp2f(x);
#endif
}
__device__ __forceinline__ float eluf(float x) {
    return x > 0.f ? x : fexp2(x * LOG2E) - 1.0f;
}
// float -> bf16 bits, round-half-up
__device__ __forceinline__ short bf16r(float x) {
    unsigned u = __float_as_uint(x);
    return (short)((u + 0x8000u) >> 16);
}
#define DOT4(c, u, p) \
    p = fmaf(c.x, u.x, fmaf(c.y, u.y, fmaf(c.z, u.z, fmaf(c.w, u.w, p))));

// ---- A: Wh = h@W via MFMA + fused f1/f2 + fused W-prep (R11 structure).
// Plain f32 Wh[b][i][64], coalesced 256-B row stores. Unchanged (verified). ----
__global__ __launch_bounds__(256) void k_wh(const float* __restrict__ h,
                                            const float* __restrict__ W,
                                            const float* __restrict__ a,
                                            float* __restrict__ Wh,
                                            float* __restrict__ f1,
                                            float* __restrict__ f2) {
    __shared__ __align__(16) unsigned char smem[34816];  // phase union
    short* lwt  = (short*)smem;               // A: [64 n][256 k] bf16 W^T (32 KB)
    float* lv   = (float*)(smem + 32768);     // A: [2][256] v1,v2 (2 KB)
    float* lred = (float*)smem;               // B: [4 wv][16*66] (16.9 KB)
    float* lp   = (float*)(smem + 16896);     // B: [2][4][16]

    int t = threadIdx.x;
    int wv = t >> 6, lane = t & 63;
    int n15 = lane & 15, q = lane >> 4;
    int bx = blockIdx.x;

    // issue tile-0 h loads early (independent of W staging)
    const float* hr = h + ((long)bx * 32 + n15) * KF + wv * 64 + q * 8;
    float4 c0 = *(const float4*)(hr);
    float4 c1 = *(const float4*)(hr + 4);
    float4 c2 = *(const float4*)(hr + 32);
    float4 c3 = *(const float4*)(hr + 36);

    // ---- in-block W prep: thread t owns W row k=t ----
    {
        const float4* wr4 = (const float4*)(W + t * DF);
        float s1 = 0.f, s2 = 0.f;
        #pragma unroll
        for (int c = 0; c < 16; c++) {
            float4 w4 = wr4[c];
            float4 a1v = *(const float4*)(a + 4 * c);        // uniform -> s_load
            float4 a2v = *(const float4*)(a + DF + 4 * c);
            lwt[(4 * c + 0) * 256 + t] = bf16r(w4.x);        // 2-way write: free
            lwt[(4 * c + 1) * 256 + t] = bf16r(w4.y);
            lwt[(4 * c + 2) * 256 + t] = bf16r(w4.z);
            lwt[(4 * c + 3) * 256 + t] = bf16r(w4.w);
            s1 = fmaf(w4.x, a1v.x, fmaf(w4.y, a1v.y, fmaf(w4.z, a1v.z, fmaf(w4.w, a1v.w, s1))));
            s2 = fmaf(w4.x, a2v.x, fmaf(w4.y, a2v.y, fmaf(w4.z, a2v.z, fmaf(w4.w, a2v.w, s2))));
        }
        lv[t] = s1;
        lv[256 + t] = s2;
    }
    __syncthreads();

    // hoist loop-invariant B-frags + v12 (one-time LDS reads)
    const short* bq = lwt + n15 * 256 + wv * 64 + q * 8;
    short8 s0b0 = *(const short8*)(bq);
    short8 s0b1 = *(const short8*)(bq + 16 * 256);
    short8 s0b2 = *(const short8*)(bq + 32 * 256);
    short8 s0b3 = *(const short8*)(bq + 48 * 256);
    short8 s1b0 = *(const short8*)(bq + 32);
    short8 s1b1 = *(const short8*)(bq + 16 * 256 + 32);
    short8 s1b2 = *(const short8*)(bq + 32 * 256 + 32);
    short8 s1b3 = *(const short8*)(bq + 48 * 256 + 32);
    const float* vv = lv + wv * 64 + q * 8;
    float4 u00 = *(const float4*)(vv);
    float4 u01 = *(const float4*)(vv + 4);
    float4 u10 = *(const float4*)(vv + 32);
    float4 u11 = *(const float4*)(vv + 36);
    float4 x00 = *(const float4*)(vv + 256);
    float4 x01 = *(const float4*)(vv + 256 + 4);
    float4 x10 = *(const float4*)(vv + 256 + 32);
    float4 x11 = *(const float4*)(vv + 256 + 36);
    __syncthreads();   // lwt/lv dead; lred region reusable

    #pragma unroll
    for (int rt = 0; rt < 2; rt++) {
        float4 m0, m1, m2, m3;
        if (rt < 1) {                         // prefetch next 16-row tile
            const float* hn = hr + 16 * KF;
            m0 = *(const float4*)(hn);
            m1 = *(const float4*)(hn + 4);
            m2 = *(const float4*)(hn + 32);
            m3 = *(const float4*)(hn + 36);
        }
        float p1 = 0.f, p2 = 0.f;
        DOT4(c0, u00, p1) DOT4(c1, u01, p1) DOT4(c2, u10, p1) DOT4(c3, u11, p1)
        DOT4(c0, x00, p2) DOT4(c1, x01, p2) DOT4(c2, x10, p2) DOT4(c3, x11, p2)

        short8 af0 = { bf16r(c0.x), bf16r(c0.y), bf16r(c0.z), bf16r(c0.w),
                       bf16r(c1.x), bf16r(c1.y), bf16r(c1.z), bf16r(c1.w) };
        short8 af1 = { bf16r(c2.x), bf16r(c2.y), bf16r(c2.z), bf16r(c2.w),
                       bf16r(c3.x), bf16r(c3.y), bf16r(c3.z), bf16r(c3.w) };
        float4v acc0 = {0.f, 0.f, 0.f, 0.f}, acc1 = acc0, acc2 = acc0, acc3 = acc0;
        acc0 = __builtin_amdgcn_mfma_f32_16x16x32_bf16(af0, s0b0, acc0, 0, 0, 0);
        acc0 = __builtin_amdgcn_mfma_f32_16x16x32_bf16(af1, s1b0, acc0, 0, 0, 0);
        acc1 = __builtin_amdgcn_mfma_f32_16x16x32_bf16(af0, s0b1, acc1, 0, 0, 0);
        acc1 = __builtin_amdgcn_mfma_f32_16x16x32_bf16(af1, s1b1, acc1, 0, 0, 0);
        acc2 = __builtin_amdgcn_mfma_f32_16x16x32_bf16(af0, s0b2, acc2, 0, 0, 0);
        acc2 = __builtin_amdgcn_mfma_f32_16x16x32_bf16(af1, s1b2, acc2, 0, 0, 0);
        acc3 = __builtin_amdgcn_mfma_f32_16x16x32_bf16(af0, s0b3, acc3, 0, 0, 0);
        acc3 = __builtin_amdgcn_mfma_f32_16x16x32_bf16(af1, s1b3, acc3, 0, 0, 0);

        #define STASH(nb, A)                                                  \
            {                                                                 \
                _Pragma("unroll")                                             \
                for (int r = 0; r < 4; r++)                                   \
                    lred[wv * 1056 + (q * 4 + r) * 66 + nb * 16 + n15] = A[r]; \
            }
        STASH(0, acc0) STASH(1, acc1) STASH(2, acc2) STASH(3, acc3)
        #undef STASH
        p1 += __shfl_xor(p1, 16, 64); p1 += __shfl_xor(p1, 32, 64);
        p2 += __shfl_xor(p2, 16, 64); p2 += __shfl_xor(p2, 32, 64);
        if (q == 0) { lp[wv * 16 + n15] = p1; lp[64 + wv * 16 + n15] = p2; }
        __syncthreads();

        long i0 = (long)bx * 32 + rt * 16;
        int d = t & 63, ig = t >> 6;
        int bb = (int)(i0 >> 11);
        int il = (int)(i0 & (N - 1));
        float s0 = 0.f, s1 = 0.f, s2 = 0.f, s3 = 0.f;
        #pragma unroll
        for (int w = 0; w < 4; w++) {
            const float* lr = lred + w * 1056 + (ig * 4) * 66 + d;
            s0 += lr[0]; s1 += lr[66]; s2 += lr[132]; s3 += lr[198];
        }
        float* wp = Wh + ((long)bb * N + il + ig * 4) * DF + d;
        wp[0]      = s0;
        wp[DF]     = s1;
        wp[2 * DF] = s2;
        wp[3 * DF] = s3;

        if (t < 16) {
            f1[i0 + t] = lp[t] + lp[16 + t] + lp[32 + t] + lp[48 + t];
        } else if (t < 32) {
            int tt = t + 48;   // 64 + (t-16)
            f2[i0 + t - 16] = lp[tt] + lp[16 + tt] + lp[32 + tt] + lp[48 + tt];
        }
        __syncthreads();
        c0 = m0; c1 = m1; c2 = m2; c3 = m3;
    }
}

// ---- B: brute-force ranks + direct denominators (NO SORT). Unchanged
// (verified R2). si[rank]=j, gA[rank]=E2/den, gsA[rank]=E2s/den,
// tIdx[i]=#{j: f2_j < -f1_i}. ----
__global__ __launch_bounds__(512) void k_rank(const float* __restrict__ f1,
                                              const float* __restrict__ f2,
                                              int* __restrict__ tIdx,
                                              int* __restrict__ si,
                                              float* __restrict__ gA,
                                              float* __restrict__ gsA) {
    __shared__ __align__(16) float4 qv[2048];   // {f1, E1, E1s, f2}
    __shared__ unsigned u2[2048];               // sortable bits of f2
    __shared__ float rS1[8][64], rS1s[8][64];
    __shared__ int   rC2[8][64], rC3[8][64];

    int t = threadIdx.x;
    int b = blockIdx.y;
    int base = blockIdx.x * 64;
    const float* f1g = f1 + b * N;
    const float* f2g = f2 + b * N;

    #pragma unroll
    for (int r = 0; r < 4; r++) {
        int idx = t + r * 512;
        float v1 = f1g[idx], v2 = f2g[idx];
        qv[idx] = make_float4(v1, fexp2(v1 * LOG2E), fexp2(v1 * 0.2f * LOG2E), v2);
        unsigned ub = __float_as_uint(v2);
        u2[idx] = ub ^ (((unsigned)((int)ub >> 31)) | 0x80000000u);
    }
    __syncthreads();

    int jl = t & 63, qt = t >> 6;       // qt wave-uniform
    int j = base + jl;
    float4 qj = qv[j];
    unsigned uj = u2[j];
    float negf2 = -qj.w, negf1 = -qj.x;
    int c2 = 0, c3 = 0;
    float S1 = 0.f, S1s = 0.f;
    int p0 = qt * 256;
    #pragma unroll 4
    for (int p = p0; p < p0 + 256; p++) {
        float4 qa = qv[p];              // broadcast b128
        unsigned up = u2[p];            // broadcast b32
        c2 += (up < uj || (up == uj && p < j)) ? 1 : 0;
        bool c = qa.x < negf2;          // f1_p < -f2_j
        S1  += c ? 0.f : qa.y;
        S1s += c ? qa.z : 0.f;
        c3 += (qa.w < negf1) ? 1 : 0;
    }
    rC2[qt][jl] = c2; rC3[qt][jl] = c3;
    rS1[qt][jl] = S1; rS1s[qt][jl] = S1s;
    __syncthreads();

    if (t < 64) {
        int j2 = base + t;
        float4 qj2 = qv[j2];
        int rank = 0, ti = 0;
        float s1 = 0.f, s1s = 0.f;
        #pragma unroll
        for (int k = 0; k < 8; k++) {
            rank += rC2[k][t]; ti += rC3[k][t];
            s1 += rS1[k][t];   s1s += rS1s[k][t];
        }
        float E2  = fexp2(qj2.w * LOG2E);
        float E2s = fexp2(qj2.w * 0.2f * LOG2E);
        float rr = 1.0f / (E2 * s1 + E2s * s1s);
        tIdx[b * N + j2] = ti;
        si [b * N + rank] = j2;          // scatter: sorted order
        gA [b * N + rank] = E2 * rr;
        gsA[b * N + rank] = E2s * rr;
    }
}

// ---- C: fused seg-sums + seg-prefix + within-seg walk + output (replaces
// k_seg + k_tab + k_out: two fewer launches, no 8.4 MB table write/read).
// Block = (64 output rows, batch). Phase A: stage si/g/gs (24 KB LDS) and
// compute all 64 segment sums (g*Wh, gs*Wh) -> LDS; serial 64-step scan
// (parallel over d) gives pG[s][d] = prefix at position 32s, pG[64] = total.
// Phase B: per row r: O = E1*(TG - PG(t_r)) + E1s*PGS(t_r), PG via seg
// lookup + <=31-step gathered walk (loop bound wave-uniform, no divergence;
// Wh gathers are L2-resident 256-B rows). ----
__global__ __launch_bounds__(256) void k_fin(const float* __restrict__ Wh,
                                             const float* __restrict__ f1,
                                             const int* __restrict__ tIdx,
                                             const int* __restrict__ si,
                                             const float* __restrict__ gA,
                                             const float* __restrict__ gsA,
                                             float* __restrict__ out) {
    __shared__ int   lsi[2048];                 // 8 KB
    __shared__ float lg[2048], lgs[2048];       // 16 KB
    __shared__ float pG[65][64], pGs[65][64];   // 32.5 KB
    __shared__ float e1v[64], e1sv[64];
    __shared__ int   tv[64];

    int t = threadIdx.x;
    int d = t & 63, q = t >> 6;                 // q = wave id (4 waves)
    int b = blockIdx.y, base = blockIdx.x * 64;
    const float* whb = Wh + (((long)b) << 11) * DF;

    // stage permutation + weights (coalesced), and per-row factors
    #pragma unroll
    for (int r = 0; r < 8; r++) {
        int p = t + r * 256;
        lsi[p] = si[b * N + p];
        lg[p]  = gA[b * N + p];
        lgs[p] = gsA[b * N + p];
    }
    if (t < 64) {
        int row = base + t;
        float v = f1[b * N + row];
        e1v[t]  = fexp2(v * LOG2E);
        e1sv[t] = fexp2(v * 0.2f * LOG2E);
        tv[t]   = tIdx[b * N + row];
        pG[0][t] = 0.f; pGs[0][t] = 0.f;
    }
    __syncthreads();

    // phase A: wave q computes segs q*16..q*16+15 (raw sums at [seg+1])
    #pragma unroll 1
    for (int s = 0; s < 16; s++) {
        int seg = q * 16 + s;
        float sg = 0.f, sgs = 0.f;
        #pragma unroll 8
        for (int x = 0; x < 32; x++) {
            int p = seg * 32 + x;
            float w = whb[lsi[p] * DF + d];     // coalesced 256-B row
            sg  = fmaf(lg[p],  w, sg);          // lg/lgs: LDS broadcast
            sgs = fmaf(lgs[p], w, sgs);
        }
        pG[seg + 1][d] = sg;
        pGs[seg + 1][d] = sgs;
    }
    __syncthreads();
    // serial seg-scan, parallel over d: wave 0 -> G, wave 1 -> Gs
    if (q == 0) {
        float run = 0.f;
        for (int s = 1; s <= 64; s++) { run += pG[s][d]; pG[s][d] = run; }
    } else if (q == 1) {
        float run = 0.f;
        for (int s = 1; s <= 64; s++) { run += pGs[s][d]; pGs[s][d] = run; }
    }
    __syncthreads();

    // phase B: wave q handles rows q*16..q*16+15
    float TG = pG[64][d];
    #pragma unroll 1
    for (int rr = 0; rr < 16; rr++) {
        int r = q * 16 + rr;
        int ti = tv[r];                          // wave-uniform
        int s = ti >> 5, e = ti & 31, p0 = s * 32;
        float pg = pG[s][d], pgs = pGs[s][d];
        for (int x = 0; x < e; x++) {            // wave-uniform bound
            int p = p0 + x;
            float w = whb[lsi[p] * DF + d];
            pg  = fmaf(lg[p],  w, pg);
            pgs = fmaf(lgs[p], w, pgs);
        }
        float o = e1v[r] * (TG - pg) + e1sv[r] * pgs;
        out[((long)b * N + base + r) * DF + d] = eluf(o);
    }
}

extern "C" void kernel_launch(void* const* d_in, const int* in_sizes, int n_in,
                              void* d_out, int out_size, void* d_ws, size_t ws_size,
                              hipStream_t stream) {
    const float* h = (const float*)d_in[0];
    const float* W = (const float*)d_in[1];
    const float* a = (const float*)d_in[2];
    float* out = (float*)d_out;

    char* ws = (char*)d_ws;
    const size_t NB = (size_t)B * N;          // 16384 rows
    size_t off = 0;
    float* Wh   = (float*)(ws + off); off += NB * DF * sizeof(float);   // 4 MB
    float* f1   = (float*)(ws + off); off += NB * sizeof(float);
    float* f2   = (float*)(ws + off); off += NB * sizeof(float);
    int*   tIdx = (int*)  (ws + off); off += NB * sizeof(int);
    int*   si   = (int*)  (ws + off); off += NB * sizeof(int);
    float* gA   = (float*)(ws + off); off += NB * sizeof(float);
    float* gsA  = (float*)(ws + off); off += NB * sizeof(float);
    (void)off; (void)ws_size;

    k_wh  <<<NB / 32, 256, 0, stream>>>(h, W, a, Wh, f1, f2);
    k_rank<<<dim3(N / 64, B), 512, 0, stream>>>(f1, f2, tIdx, si, gA, gsA);
    k_fin <<<dim3(N / 64, B), 256, 0, stream>>>(Wh, f1, tIdx, si, gA, gsA, out);
}

// Round 5
// 114.941 us; speedup vs baseline: 1.2256x; 1.2256x over previous
//
#include <hip/hip_runtime.h>

#define B 8
#define N 2048
#define KF 256
#define DF 64
#define LOG2E 1.44269504088896340736f
#define NR 2049   // prefix-table rows per batch (row 2048 = total/zero row)

typedef __attribute__((ext_vector_type(8))) short short8;   // 8 bf16 (4 VGPRs)
typedef __attribute__((ext_vector_type(4))) float float4v;  // MFMA C/D frag

__device__ __forceinline__ float fexp2(float x) {
#if __has_builtin(__builtin_amdgcn_exp2f)
    return __builtin_amdgcn_exp2f(x);
#else
    return exp2f(x);
#endif
}
__device__ __forceinline__ float eluf(float x) {
    return x > 0.f ? x : fexp2(x * LOG2E) - 1.0f;
}
// float -> bf16 bits, round-half-up
__device__ __forceinline__ short bf16r(float x) {
    unsigned u = __float_as_uint(x);
    return (short)((u + 0x8000u) >> 16);
}
// monotone float -> sortable uint key (order-preserving for all finite values)
__device__ __forceinline__ unsigned sortkey(float x) {
    unsigned u = __float_as_uint(x);
    return u ^ (((unsigned)((int)u >> 31)) | 0x80000000u);
}
#define DOT4(c, u, p) \
    p = fmaf(c.x, u.x, fmaf(c.y, u.y, fmaf(c.z, u.z, fmaf(c.w, u.w, p))));

// ---- A: Wh = h@W via MFMA + fused f1/f2 + fused W-prep (verified R2/R3).
// Additions: (1) zero the 256 KB segG/segGs atomic target (128 floats per
// block); (2) emit qpack[row] = {key(f1), key(f2), E1, E1s} so k_rank's
// p-stream can ride the scalar pipe. ----
__global__ __launch_bounds__(256) void k_wh(const float* __restrict__ h,
                                            const float* __restrict__ W,
                                            const float* __restrict__ a,
                                            float* __restrict__ Wh,
                                            float* __restrict__ f1,
                                            float* __restrict__ f2,
                                            float4* __restrict__ qpack,
                                            float* __restrict__ segzero) {
    __shared__ __align__(16) unsigned char smem[34816];  // phase union
    short* lwt  = (short*)smem;               // A: [64 n][256 k] bf16 W^T (32 KB)
    float* lv   = (float*)(smem + 32768);     // A: [2][256] v1,v2 (2 KB)
    float* lred = (float*)smem;               // B: [4 wv][16*66] (16.9 KB)
    float* lp   = (float*)(smem + 16896);     // B: [2][4][16]

    int t = threadIdx.x;
    int wv = t >> 6, lane = t & 63;
    int n15 = lane & 15, q = lane >> 4;
    int bx = blockIdx.x;

    if (t < 128) segzero[bx * 128 + t] = 0.f;   // 512 blocks x 128 = 64K floats

    // issue tile-0 h loads early (independent of W staging)
    const float* hr = h + ((long)bx * 32 + n15) * KF + wv * 64 + q * 8;
    float4 c0 = *(const float4*)(hr);
    float4 c1 = *(const float4*)(hr + 4);
    float4 c2 = *(const float4*)(hr + 32);
    float4 c3 = *(const float4*)(hr + 36);

    // ---- in-block W prep: thread t owns W row k=t ----
    {
        const float4* wr4 = (const float4*)(W + t * DF);
        float s1 = 0.f, s2 = 0.f;
        #pragma unroll
        for (int c = 0; c < 16; c++) {
            float4 w4 = wr4[c];
            float4 a1v = *(const float4*)(a + 4 * c);        // uniform -> s_load
            float4 a2v = *(const float4*)(a + DF + 4 * c);
            lwt[(4 * c + 0) * 256 + t] = bf16r(w4.x);        // 2-way write: free
            lwt[(4 * c + 1) * 256 + t] = bf16r(w4.y);
            lwt[(4 * c + 2) * 256 + t] = bf16r(w4.z);
            lwt[(4 * c + 3) * 256 + t] = bf16r(w4.w);
            s1 = fmaf(w4.x, a1v.x, fmaf(w4.y, a1v.y, fmaf(w4.z, a1v.z, fmaf(w4.w, a1v.w, s1))));
            s2 = fmaf(w4.x, a2v.x, fmaf(w4.y, a2v.y, fmaf(w4.z, a2v.z, fmaf(w4.w, a2v.w, s2))));
        }
        lv[t] = s1;
        lv[256 + t] = s2;
    }
    __syncthreads();

    // hoist loop-invariant B-frags + v12 (one-time LDS reads)
    const short* bq = lwt + n15 * 256 + wv * 64 + q * 8;
    short8 s0b0 = *(const short8*)(bq);
    short8 s0b1 = *(const short8*)(bq + 16 * 256);
    short8 s0b2 = *(const short8*)(bq + 32 * 256);
    short8 s0b3 = *(const short8*)(bq + 48 * 256);
    short8 s1b0 = *(const short8*)(bq + 32);
    short8 s1b1 = *(const short8*)(bq + 16 * 256 + 32);
    short8 s1b2 = *(const short8*)(bq + 32 * 256 + 32);
    short8 s1b3 = *(const short8*)(bq + 48 * 256 + 32);
    const float* vv = lv + wv * 64 + q * 8;
    float4 u00 = *(const float4*)(vv);
    float4 u01 = *(const float4*)(vv + 4);
    float4 u10 = *(const float4*)(vv + 32);
    float4 u11 = *(const float4*)(vv + 36);
    float4 x00 = *(const float4*)(vv + 256);
    float4 x01 = *(const float4*)(vv + 256 + 4);
    float4 x10 = *(const float4*)(vv + 256 + 32);
    float4 x11 = *(const float4*)(vv + 256 + 36);
    __syncthreads();   // lwt/lv dead; lred region reusable

    #pragma unroll
    for (int rt = 0; rt < 2; rt++) {
        float4 m0, m1, m2, m3;
        if (rt < 1) {                         // prefetch next 16-row tile
            const float* hn = hr + 16 * KF;
            m0 = *(const float4*)(hn);
            m1 = *(const float4*)(hn + 4);
            m2 = *(const float4*)(hn + 32);
            m3 = *(const float4*)(hn + 36);
        }
        float p1 = 0.f, p2 = 0.f;
        DOT4(c0, u00, p1) DOT4(c1, u01, p1) DOT4(c2, u10, p1) DOT4(c3, u11, p1)
        DOT4(c0, x00, p2) DOT4(c1, x01, p2) DOT4(c2, x10, p2) DOT4(c3, x11, p2)

        short8 af0 = { bf16r(c0.x), bf16r(c0.y), bf16r(c0.z), bf16r(c0.w),
                       bf16r(c1.x), bf16r(c1.y), bf16r(c1.z), bf16r(c1.w) };
        short8 af1 = { bf16r(c2.x), bf16r(c2.y), bf16r(c2.z), bf16r(c2.w),
                       bf16r(c3.x), bf16r(c3.y), bf16r(c3.z), bf16r(c3.w) };
        float4v acc0 = {0.f, 0.f, 0.f, 0.f}, acc1 = acc0, acc2 = acc0, acc3 = acc0;
        acc0 = __builtin_amdgcn_mfma_f32_16x16x32_bf16(af0, s0b0, acc0, 0, 0, 0);
        acc0 = __builtin_amdgcn_mfma_f32_16x16x32_bf16(af1, s1b0, acc0, 0, 0, 0);
        acc1 = __builtin_amdgcn_mfma_f32_16x16x32_bf16(af0, s0b1, acc1, 0, 0, 0);
        acc1 = __builtin_amdgcn_mfma_f32_16x16x32_bf16(af1, s1b1, acc1, 0, 0, 0);
        acc2 = __builtin_amdgcn_mfma_f32_16x16x32_bf16(af0, s0b2, acc2, 0, 0, 0);
        acc2 = __builtin_amdgcn_mfma_f32_16x16x32_bf16(af1, s1b2, acc2, 0, 0, 0);
        acc3 = __builtin_amdgcn_mfma_f32_16x16x32_bf16(af0, s0b3, acc3, 0, 0, 0);
        acc3 = __builtin_amdgcn_mfma_f32_16x16x32_bf16(af1, s1b3, acc3, 0, 0, 0);

        #define STASH(nb, A)                                                  \
            {                                                                 \
                _Pragma("unroll")                                             \
                for (int r = 0; r < 4; r++)                                   \
                    lred[wv * 1056 + (q * 4 + r) * 66 + nb * 16 + n15] = A[r]; \
            }
        STASH(0, acc0) STASH(1, acc1) STASH(2, acc2) STASH(3, acc3)
        #undef STASH
        p1 += __shfl_xor(p1, 16, 64); p1 += __shfl_xor(p1, 32, 64);
        p2 += __shfl_xor(p2, 16, 64); p2 += __shfl_xor(p2, 32, 64);
        if (q == 0) { lp[wv * 16 + n15] = p1; lp[64 + wv * 16 + n15] = p2; }
        __syncthreads();

        long i0 = (long)bx * 32 + rt * 16;
        int d = t & 63, ig = t >> 6;
        int bb = (int)(i0 >> 11);
        int il = (int)(i0 & (N - 1));
        float s0 = 0.f, s1 = 0.f, s2 = 0.f, s3 = 0.f;
        #pragma unroll
        for (int w = 0; w < 4; w++) {
            const float* lr = lred + w * 1056 + (ig * 4) * 66 + d;
            s0 += lr[0]; s1 += lr[66]; s2 += lr[132]; s3 += lr[198];
        }
        float* wp = Wh + ((long)bb * N + il + ig * 4) * DF + d;
        wp[0]      = s0;
        wp[DF]     = s1;
        wp[2 * DF] = s2;
        wp[3 * DF] = s3;

        if (t < 16) {
            float v1 = lp[t] + lp[16 + t] + lp[32 + t] + lp[48 + t];
            f1[i0 + t] = v1;
            // same terms/order as the f2 path below -> bitwise-identical value
            float v2 = lp[64 + t] + lp[80 + t] + lp[96 + t] + lp[112 + t];
            float4 qe;
            qe.x = __uint_as_float(sortkey(v1));
            qe.y = __uint_as_float(sortkey(v2));
            qe.z = fexp2(v1 * LOG2E);
            qe.w = fexp2(v1 * 0.2f * LOG2E);
            qpack[i0 + t] = qe;
        } else if (t < 32) {
            int tt = t + 48;   // 64 + (t-16)
            f2[i0 + t - 16] = lp[tt] + lp[16 + tt] + lp[32 + tt] + lp[48 + tt];
        }
        __syncthreads();
        c0 = m0; c1 = m1; c2 = m2; c3 = m3;
    }
}

// ---- B: ranks + denominators on the SCALAR pipe + fused segment sums.
// Wave-uniform p-stream read via readfirstlane'd pointer -> s_load_dwordx4;
// no LDS staging, no per-block exp recompute. Key-space compares (boundary
// equality is output-invariant: e=0 gives exp(0) on both LeakyReLU branches).
// Finalize scatters si/g/gs AND atomically accumulates segG/segGs
// (replaces k_seg: one fewer dispatch). ----
__global__ __launch_bounds__(512) void k_rank(const float4* __restrict__ qpack,
                                              const float* __restrict__ f1,
                                              const float* __restrict__ f2,
                                              const float* __restrict__ Wh,
                                              int* __restrict__ tIdx,
                                              int* __restrict__ si,
                                              float* __restrict__ gA,
                                              float* __restrict__ gsA,
                                              float* __restrict__ segG,
                                              float* __restrict__ segGs) {
    __shared__ float rS1[8][64], rS1s[8][64];
    __shared__ int   rC2[8][64], rC3[8][64];
    __shared__ float gL[64], gsL[64];
    __shared__ int   rkL[64];

    int t = threadIdx.x;
    int b = blockIdx.y, base = blockIdx.x * 64;
    int jl = t & 63;
    int j = base + jl;
    float f1j = f1[(long)b * N + j];
    float f2j = f2[(long)b * N + j];
    unsigned u2j = sortkey(f2j);
    unsigned long long Kj = (((unsigned long long)u2j) << 32) | (unsigned)j;
    unsigned vkNf2 = sortkey(-f2j);   // S-sum split: f1_p < -f2_j
    unsigned vkNf1 = sortkey(-f1j);   // threshold:   f2_p < -f1_j

    int qt = __builtin_amdgcn_readfirstlane(t >> 6);       // wave id, uniform
    const float4* qp = qpack + (long)b * N + qt * 256;     // uniform -> s_load
    int c2 = 0, c3 = 0;
    float S1 = 0.f, S1s = 0.f;
    #pragma unroll 8
    for (int x = 0; x < 256; x++) {
        float4 e = qp[x];
        unsigned u1p = __float_as_uint(e.x);
        unsigned u2p = __float_as_uint(e.y);
        unsigned long long Kp = (((unsigned long long)u2p) << 32)
                              | (unsigned)(qt * 256 + x);
        c2 += (Kp < Kj) ? 1 : 0;          // rank (lexicographic, unique)
        c3 += (u2p < vkNf1) ? 1 : 0;      // threshold count
        bool cc = u1p < vkNf2;            // 0.2-branch membership
        S1  += cc ? 0.f : e.z;            // E1 suffix mass
        S1s += cc ? e.w : 0.f;            // E1s prefix mass
    }
    rC2[qt][jl] = c2; rC3[qt][jl] = c3;
    rS1[qt][jl] = S1; rS1s[qt][jl] = S1s;
    __syncthreads();

    if (t < 64) {                          // jl == t here, j = base + t
        int rank = 0, ti = 0;
        float s1 = 0.f, s1s = 0.f;
        #pragma unroll
        for (int k = 0; k < 8; k++) {
            rank += rC2[k][t]; ti += rC3[k][t];
            s1 += rS1[k][t];   s1s += rS1s[k][t];
        }
        float E2  = fexp2(f2j * LOG2E);
        float E2s = fexp2(f2j * 0.2f * LOG2E);
        float rr = 1.0f / (E2 * s1 + E2s * s1s);
        float g = E2 * rr, gs = E2s * rr;
        tIdx[(long)b * N + j] = ti;
        si [(long)b * N + rank] = j;       // scatter: sorted order
        gA [(long)b * N + rank] = g;
        gsA[(long)b * N + rank] = gs;
        rkL[t] = rank; gL[t] = g; gsL[t] = gs;
    }
    __syncthreads();

    // fused segment accumulation (was k_seg): thread = (row-group, d)
    int d = t & 63, rg = t >> 6;
    const float* whb = Wh + (((long)b) << 11) * DF;
    #pragma unroll
    for (int r = 0; r < 8; r++) {
        int lr = rg * 8 + r;               // local row 0..63 (wave-uniform)
        int row = base + lr;
        float w = whb[row * DF + d];       // coalesced 256-B row
        int seg = rkL[lr] >> 5;            // LDS broadcast
        atomicAdd(&segG [(b * 64 + seg) * DF + d], gL[lr] * w);
        atomicAdd(&segGs[(b * 64 + seg) * DF + d], gsL[lr] * w);
    }
}

// ---- C: table emission (verified R2, verbatim). Per (b,seg) block:
// seg-level prefix/total from segG/segGs, then within-seg unrolled walk
// writing SSg (suffix of g*Wh) and PSgs (excl prefix of gs*Wh) rows. ----
__global__ __launch_bounds__(256) void k_tab(const float* __restrict__ Wh,
                                             const int* __restrict__ si,
                                             const float* __restrict__ gA,
                                             const float* __restrict__ gsA,
                                             const float* __restrict__ segG,
                                             const float* __restrict__ segGs,
                                             float* __restrict__ SSg,
                                             float* __restrict__ PSgs) {
    __shared__ float lPG[4][64], lPGs[4][64];   // sub-partial seg prefixes
    __shared__ float lTG[4][64], lTGs[4][64];   // sub-partial seg totals
    __shared__ float wG[4][64],  wGs[4][64];    // within-seg sub sums
    int t = threadIdx.x;
    int d = t & 63, sub = t >> 6;
    int seg = blockIdx.x, b = blockIdx.y;

    const float* sgb  = segG  + (b * 64) * DF + d;
    const float* sgsb = segGs + (b * 64) * DF + d;
    float pg = 0.f, pgs = 0.f, tg = 0.f, tgs = 0.f;
    #pragma unroll
    for (int k = 0; k < 16; k++) {
        int s = sub * 16 + k;
        float vg = sgb[s * DF], vgs = sgsb[s * DF];
        tg += vg; tgs += vgs;
        if (s < seg) { pg += vg; pgs += vgs; }
    }
    lPG[sub][d] = pg; lPGs[sub][d] = pgs;
    lTG[sub][d] = tg; lTGs[sub][d] = tgs;

    int p0 = seg * 32 + sub * 8;
    const int*   sib = si  + b * N;
    const float* ga  = gA  + b * N;
    const float* gsa = gsA + b * N;
    const float* whb = Wh + (((long)b) << 11) * DF;
    float rows[8], gv[8], gsv[8];
    float sg = 0.f, sgs = 0.f;
    #pragma unroll
    for (int x = 0; x < 8; x++) {
        int p = p0 + x;
        int r = sib[p];
        float wv = whb[r * DF + d];
        rows[x] = wv; gv[x] = ga[p]; gsv[x] = gsa[p];
        sg  = fmaf(gv[x],  wv, sg);
        sgs = fmaf(gsv[x], wv, sgs);
    }
    wG[sub][d] = sg; wGs[sub][d] = sgs;
    __syncthreads();

    float totG  = lTG[0][d] + lTG[1][d] + lTG[2][d] + lTG[3][d];
    float baseG  = lPG[0][d] + lPG[1][d] + lPG[2][d] + lPG[3][d];
    float baseGs = lPGs[0][d] + lPGs[1][d] + lPGs[2][d] + lPGs[3][d];
    #pragma unroll
    for (int k = 0; k < 3; k++) {
        if (k < sub) { baseG += wG[k][d]; baseGs += wGs[k][d]; }
    }

    float* ssb = SSg  + ((long)b * NR) * DF + d;
    float* psb = PSgs + ((long)b * NR) * DF + d;
    float rg = baseG, rgs = baseGs;
    #pragma unroll
    for (int x = 0; x < 8; x++) {
        long p = p0 + x;
        ssb[p * DF] = totG - rg;
        psb[p * DF] = rgs;
        rg  = fmaf(gv[x],  rows[x], rg);
        rgs = fmaf(gsv[x], rows[x], rgs);
    }
    if (seg == 63 && sub == 3) {
        ssb[2048L * DF] = 0.f;          // exact zero suffix
        psb[2048L * DF] = rgs;          // full prefix total
    }
}

// ---- D: output (verified R2, verbatim).
// O[i,:] = elu( E1_i * SSg[t_i,:] + E1s_i * PSgs[t_i,:] ). ----
__global__ __launch_bounds__(256) void k_out(const float* __restrict__ f1,
                                             const int* __restrict__ tIdx,
                                             const float* __restrict__ SSg,
                                             const float* __restrict__ PSgs,
                                             float* __restrict__ out) {
    int t = threadIdx.x;
    int b = blockIdx.y;
    int i0 = blockIdx.x * 64;
    int rr = t >> 6, d = t & 63;
    const float* sgB = SSg  + ((long)b * NR) * DF + d;
    const float* pgB = PSgs + ((long)b * NR) * DF + d;
    float* ob = out + ((long)b * N + i0) * DF + d;
    #pragma unroll
    for (int kk = 0; kk < 16; kk++) {
        int r = rr + kk * 4;
        int ti = tIdx[b * N + i0 + r];                 // wave-uniform
        float v = f1[b * N + i0 + r];
        float e1  = fexp2(v * LOG2E);
        float e1s = fexp2(v * 0.2f * LOG2E);
        float x = e1 * sgB[(long)ti * DF] + e1s * pgB[(long)ti * DF];
        ob[(long)r * DF] = eluf(x);
    }
}

extern "C" void kernel_launch(void* const* d_in, const int* in_sizes, int n_in,
                              void* d_out, int out_size, void* d_ws, size_t ws_size,
                              hipStream_t stream) {
    const float* h = (const float*)d_in[0];
    const float* W = (const float*)d_in[1];
    const float* a = (const float*)d_in[2];
    float* out = (float*)d_out;

    char* ws = (char*)d_ws;
    const size_t NB = (size_t)B * N;          // 16384 rows
    size_t off = 0;
    float*  Wh    = (float*) (ws + off); off += NB * DF * sizeof(float);   // 4 MB
    float*  f1    = (float*) (ws + off); off += NB * sizeof(float);
    float*  f2    = (float*) (ws + off); off += NB * sizeof(float);
    int*    tIdx  = (int*)   (ws + off); off += NB * sizeof(int);
    int*    si    = (int*)   (ws + off); off += NB * sizeof(int);
    float*  gA    = (float*) (ws + off); off += NB * sizeof(float);
    float*  gsA   = (float*) (ws + off); off += NB * sizeof(float);
    float4* qpack = (float4*)(ws + off); off += NB * sizeof(float4);       // 256 KB
    float*  segG  = (float*) (ws + off); off += (size_t)B * 64 * DF * sizeof(float); // 128 KB
    float*  segGs = (float*) (ws + off); off += (size_t)B * 64 * DF * sizeof(float); // 128 KB (contiguous with segG)
    float*  SSg   = (float*) (ws + off); off += (size_t)B * NR * DF * sizeof(float); // 4.2 MB
    float*  PSgs  = (float*) (ws + off); off += (size_t)B * NR * DF * sizeof(float); // 4.2 MB
    (void)off; (void)ws_size;

    k_wh  <<<NB / 32, 256, 0, stream>>>(h, W, a, Wh, f1, f2, qpack, segG);
    k_rank<<<dim3(N / 64, B), 512, 0, stream>>>(qpack, f1, f2, Wh, tIdx, si, gA, gsA, segG, segGs);
    k_tab <<<dim3(64, B), 256, 0, stream>>>(Wh, si, gA, gsA, segG, segGs, SSg, PSgs);
    k_out <<<dim3(N / 64, B), 256, 0, stream>>>(f1, tIdx, SSg, PSgs, out);
}